// Round 11
// baseline (109.558 us; speedup 1.0000x reference)
//
#include <hip/hip_runtime.h>

#define N_NEURONS 1024
#define TABLE_SIZE 65536
#define BATCH 8192
#define RPB 4                        // table rows (neurons) per block
#define NBLK (N_NEURONS / RPB)       // 256 blocks, 1 per CU
#define TPB 1024                     // 16 waves per block
#define QSIZE 16384                  // floats per stage (64 KB LDS)
#define NQ (TABLE_SIZE / QSIZE)      // 4 stages per row
#define SPT (BATCH / TPB)            // 8 samples per thread
#define TS ((size_t)TABLE_SIZE)

// Row-streaming formulation: instead of 8.4M random 64-B line requests
// (measured ceiling ~6 TB/s of line traffic regardless of HBM vs LLC source,
// R6-R10), stream the table exactly once, fully coalesced, through LDS and
// serve the random 4-B gathers from LDS banks (no line-granularity waste).
// Block b owns rows [4b, 4b+4). Per (row, quarter): stage 64 KB into LDS,
// then every thread tests its 8 samples' indices and accumulates hits.
__global__ __launch_bounds__(TPB) void qw_stage_kernel(
    const int* __restrict__ data,
    const float* __restrict__ table,
    float* __restrict__ part)        // [NBLK][BATCH]
{
    __shared__ float lds[QSIZE];

    const int b = blockIdx.x;
    const int t = threadIdx.x;

    // Preload this thread's 8 samples' indices for the block's 4 rows.
    // data[s][4b..4b+3] as one int4: 16-B aligned, every fetched byte used.
    int4 qidx[SPT];
#pragma unroll
    for (int k = 0; k < SPT; ++k) {
        const int s = t * SPT + k;
        qidx[k] = *reinterpret_cast<const int4*>(
            data + (size_t)s * N_NEURONS + b * RPB);
    }

    float acc[SPT];
#pragma unroll
    for (int k = 0; k < SPT; ++k) acc[k] = 0.0f;

#pragma unroll
    for (int r = 0; r < RPB; ++r) {
        const float* __restrict__ trow = table + (size_t)(b * RPB + r) * TS;
#pragma unroll
        for (int q = 0; q < NQ; ++q) {
            // stage 64 KB of row (b*4+r) into LDS, fully coalesced float4
            const float* __restrict__ src = trow + q * QSIZE;
#pragma unroll
            for (int j = 0; j < QSIZE / (TPB * 4); ++j) {   // 4 iterations
                const int o = j * TPB * 4 + t * 4;
                *reinterpret_cast<float4*>(&lds[o]) =
                    *reinterpret_cast<const float4*>(src + o);
            }
            __syncthreads();

            const int lo = q * QSIZE;
#pragma unroll
            for (int k = 0; k < SPT; ++k) {
                const int idx = (r == 0) ? qidx[k].x
                              : (r == 1) ? qidx[k].y
                              : (r == 2) ? qidx[k].z
                              :            qidx[k].w;
                const unsigned rel = (unsigned)(idx - lo);
                if (rel < (unsigned)QSIZE) acc[k] += lds[rel];
            }
            __syncthreads();        // protect LDS before next stage overwrites
        }
    }

    // per-block per-sample partials, coalesced (8 consecutive floats/thread)
    float* __restrict__ dst = part + (size_t)b * BATCH + t * SPT;
#pragma unroll
    for (int k = 0; k < SPT; ++k) dst[k] = acc[k];
}

// out[i] = sum_b part[b][i]   (8 MB streamed, coalesced per iteration)
__global__ __launch_bounds__(256) void qw_reduce_kernel(
    const float* __restrict__ part,
    float* __restrict__ out)
{
    const int i = blockIdx.x * 256 + threadIdx.x;
    float s0 = 0.0f, s1 = 0.0f, s2 = 0.0f, s3 = 0.0f;
#pragma unroll 4
    for (int b = 0; b < NBLK; b += 4) {
        s0 += part[(size_t)(b + 0) * BATCH + i];
        s1 += part[(size_t)(b + 1) * BATCH + i];
        s2 += part[(size_t)(b + 2) * BATCH + i];
        s3 += part[(size_t)(b + 3) * BATCH + i];
    }
    out[i] = (s0 + s1) + (s2 + s3);
}

// Mid fallback (ws >= 256 KB): R2-style neuron-major partials, ~92 us.
#define MF_NGROUPS 8
#define MF_NPG 128
#define MF_SPB 128
__global__ __launch_bounds__(256) void qw_partial_kernel(
    const int* __restrict__ data,
    const float* __restrict__ table,
    float* __restrict__ part)           // [MF_NGROUPS][BATCH]
{
    const int b      = blockIdx.x;
    const int g      = b & (MF_NGROUPS - 1);
    const int sub    = b >> 3;
    const int t      = threadIdx.x;
    const int h      = t >> 7;                       // 0 or 1
    const int sid    = t & (MF_SPB - 1);
    const int sample = sub * MF_SPB + sid;
    const int jbase  = g * MF_NPG + h * 64;

    const int* __restrict__ drow = data + (size_t)sample * N_NEURONS + jbase;
    float acc = 0.0f;
#pragma unroll
    for (int jo = 0; jo < 64; jo += 16) {
        const int4 i0 = *reinterpret_cast<const int4*>(drow + jo);
        const int4 i1 = *reinterpret_cast<const int4*>(drow + jo + 4);
        const int4 i2 = *reinterpret_cast<const int4*>(drow + jo + 8);
        const int4 i3 = *reinterpret_cast<const int4*>(drow + jo + 12);
        const float* __restrict__ tp = table + (size_t)(jbase + jo) * TS;
        acc += tp[(size_t) 0 * TS + i0.x] + tp[(size_t) 1 * TS + i0.y]
             + tp[(size_t) 2 * TS + i0.z] + tp[(size_t) 3 * TS + i0.w]
             + tp[(size_t) 4 * TS + i1.x] + tp[(size_t) 5 * TS + i1.y]
             + tp[(size_t) 6 * TS + i1.z] + tp[(size_t) 7 * TS + i1.w]
             + tp[(size_t) 8 * TS + i2.x] + tp[(size_t) 9 * TS + i2.y]
             + tp[(size_t)10 * TS + i2.z] + tp[(size_t)11 * TS + i2.w]
             + tp[(size_t)12 * TS + i3.x] + tp[(size_t)13 * TS + i3.y]
             + tp[(size_t)14 * TS + i3.z] + tp[(size_t)15 * TS + i3.w];
    }
    __shared__ float lsum[MF_SPB];
    if (h == 0) lsum[sid] = acc;
    __syncthreads();
    if (h == 1) part[(size_t)g * BATCH + sample] = lsum[sid] + acc;
}

__global__ __launch_bounds__(256) void qw_reduce8_kernel(
    const float* __restrict__ part,
    float* __restrict__ out)
{
    const int i = blockIdx.x * 256 + threadIdx.x;
    float s = 0.0f;
#pragma unroll
    for (int g = 0; g < MF_NGROUPS; ++g) s += part[(size_t)g * BATCH + i];
    out[i] = s;
}

// Last-resort fallback (no workspace).
__global__ __launch_bounds__(256) void qw_gather_kernel(
    const int* __restrict__ data,
    const float* __restrict__ table,
    float* __restrict__ out)
{
    const int gtid   = blockIdx.x * blockDim.x + threadIdx.x;
    const int sample = gtid >> 6;
    const int lane   = threadIdx.x & 63;
    if (sample >= BATCH) return;
    const int* __restrict__ row = data + (size_t)sample * N_NEURONS;
    float acc = 0.0f;
#pragma unroll
    for (int k = 0; k < 4; ++k) {
        const int jb = 256 * k + 4 * lane;
        const int4 idx4 = *reinterpret_cast<const int4*>(row + jb);
        acc += table[(size_t)(jb + 0) * TS + idx4.x];
        acc += table[(size_t)(jb + 1) * TS + idx4.y];
        acc += table[(size_t)(jb + 2) * TS + idx4.z];
        acc += table[(size_t)(jb + 3) * TS + idx4.w];
    }
#pragma unroll
    for (int off = 32; off >= 1; off >>= 1) acc += __shfl_xor(acc, off, 64);
    if (lane == 0) out[sample] = acc;
}

extern "C" void kernel_launch(void* const* d_in, const int* in_sizes, int n_in,
                              void* d_out, int out_size, void* d_ws, size_t ws_size,
                              hipStream_t stream)
{
    const int*   data  = (const int*)d_in[0];    // [BATCH, N_NEURONS] int32
    const float* table = (const float*)d_in[1];  // [N_NEURONS, TABLE_SIZE] float32
    float*       out   = (float*)d_out;          // [BATCH] float32

    const size_t stage_bytes = (size_t)NBLK * BATCH * sizeof(float);      // 8 MB
    const size_t mid_bytes   = (size_t)MF_NGROUPS * BATCH * sizeof(float); // 256 KB

    if (ws_size >= stage_bytes) {
        float* part = (float*)d_ws;
        qw_stage_kernel<<<NBLK, TPB, 0, stream>>>(data, table, part);
        qw_reduce_kernel<<<BATCH / 256, 256, 0, stream>>>(part, out);
    } else if (ws_size >= mid_bytes) {
        float* part = (float*)d_ws;
        qw_partial_kernel<<<(BATCH / MF_SPB) * MF_NGROUPS, 256, 0, stream>>>(
            data, table, part);
        qw_reduce8_kernel<<<BATCH / 256, 256, 0, stream>>>(part, out);
    } else {
        qw_gather_kernel<<<BATCH / 4, 256, 0, stream>>>(data, table, out);
    }
}